// Round 3
// baseline (263.055 us; speedup 1.0000x reference)
//
#include <hip/hip_runtime.h>

#define BATCH 64
#define T 480000
#define NTAPS 16
#define T16 (T / 16)        // 30000 16-float tiles per row

typedef float floatx4 __attribute__((ext_vector_type(4)));

// One thread computes 16 consecutive outputs of one row.
// Needs x[t0-15 .. t0+15] -> 8 aligned float4 chunks (indices 4*c16-4 .. 4*c16+3).
__global__ __launch_bounds__(256) void fir_apply_kernel(
    const float* __restrict__ x,
    const float* __restrict__ b,
    float* __restrict__ y)
{
    const int gid = blockIdx.x * blockDim.x + threadIdx.x;
    if (gid >= BATCH * T16) return;

    const int row = gid / T16;
    const int c16 = gid - row * T16;

    const floatx4* xr = (const floatx4*)(x + (size_t)row * T);

    // s[0..31] = x[row, 16*c16-16 .. 16*c16+15], zeros for t < 0.
    // Chunks are float4-aligned: each chunk is entirely t>=0 or entirely t<0,
    // and only the c16==0 threads (1 per row) take the zero path.
    float s[32];
#pragma unroll
    for (int m = 0; m < 8; ++m) {
        const int c = 4 * c16 - 4 + m;
        floatx4 v;
        if (c >= 0) {
            v = xr[c];
        } else {
            v = (floatx4){0.f, 0.f, 0.f, 0.f};
        }
        s[4 * m + 0] = v.x;
        s[4 * m + 1] = v.y;
        s[4 * m + 2] = v.z;
        s[4 * m + 3] = v.w;
    }

    // Taps: wave-uniform address, literal indices -> scalar loads.
    float tap[NTAPS];
#pragma unroll
    for (int k = 0; k < NTAPS; ++k) tap[k] = b[k];

    // y[16*c16 + j] = sum_k tap[k] * s[16 + j - k],  j in [0,16)
    float acc[16];
#pragma unroll
    for (int j = 0; j < 16; ++j) {
        float a = 0.f;
#pragma unroll
        for (int k = 0; k < NTAPS; ++k) {
            a += tap[k] * s[16 + j - k];
        }
        acc[j] = a;
    }

    // Nontemporal stores: y is write-once, keep it out of L2/LLC so x stays hot.
    floatx4* yr = (floatx4*)(y + (size_t)row * T) + 4 * (size_t)c16;
#pragma unroll
    for (int m = 0; m < 4; ++m) {
        floatx4 v = {acc[4 * m + 0], acc[4 * m + 1],
                     acc[4 * m + 2], acc[4 * m + 3]};
        __builtin_nontemporal_store(v, yr + m);
    }
}

extern "C" void kernel_launch(void* const* d_in, const int* in_sizes, int n_in,
                              void* d_out, int out_size, void* d_ws, size_t ws_size,
                              hipStream_t stream)
{
    const float* x = (const float*)d_in[0];
    const float* b = (const float*)d_in[1];
    float* y = (float*)d_out;

    const int total = BATCH * T16;                 // 1,920,000 threads
    const int block = 256;
    const int grid = (total + block - 1) / block;  // exactly 7500

    fir_apply_kernel<<<grid, block, 0, stream>>>(x, b, y);
}

// Round 4
// 215.601 us; speedup vs baseline: 1.2201x; 1.2201x over previous
//
#include <hip/hip_runtime.h>

#define BATCH 64
#define T 480000
#define T4 (T / 4)              // 120000 float4 chunks per row
#define NTAPS 16
#define NC (BATCH * T4)         // 7,680,000 total chunks; flat idx -> y chunk idx

typedef float floatx4 __attribute__((ext_vector_type(4)));

// Load the 5 chunks (halo 4 + own 1) needed for output chunk `idx`.
// Branchless: clamp address, cndmask zeros for t<0 (only first chunk of each row).
__device__ __forceinline__ void load5(const float* __restrict__ x, int idx,
                                      floatx4 v[5])
{
    const unsigned row  = (unsigned)idx / (unsigned)T4;   // magic-mul div
    const int      col4 = idx - (int)(row * T4);
    const floatx4* xr   = (const floatx4*)(x + (size_t)row * T);
#pragma unroll
    for (int m = 0; m < 5; ++m) {
        const int c  = col4 - 4 + m;
        const int cc = c < 0 ? 0 : c;
        floatx4 t = xr[cc];
        if (c < 0) t = (floatx4){0.f, 0.f, 0.f, 0.f};
        v[m] = t;
    }
}

__global__ __launch_bounds__(256) void fir_apply_kernel(
    const float* __restrict__ x,
    const float* __restrict__ b,
    float* __restrict__ y)
{
    // Taps: wave-uniform address, literal indices -> s_loads, live in SGPRs.
    float tap[NTAPS];
#pragma unroll
    for (int k = 0; k < NTAPS; ++k) tap[k] = b[k];

    const int stride = gridDim.x * blockDim.x;
    int idx = blockIdx.x * blockDim.x + threadIdx.x;
    if (idx >= NC) return;

    floatx4* yv = (floatx4*)y;

    floatx4 v[5];
    load5(x, idx, v);               // prologue prefetch

    for (;;) {
        const int nidx = idx + stride;
        const bool have_next = nidx < NC;

        // Software pipeline: issue next iteration's loads before computing.
        floatx4 w[5];
        if (have_next) load5(x, nidx, w);

        // s[0..19] = the 20 staged samples; y[4*idx+j] needs s[16+j-k].
        float s[20];
#pragma unroll
        for (int m = 0; m < 5; ++m) {
            s[4 * m + 0] = v[m].x;
            s[4 * m + 1] = v[m].y;
            s[4 * m + 2] = v[m].z;
            s[4 * m + 3] = v[m].w;
        }

        float acc[4];
#pragma unroll
        for (int j = 0; j < 4; ++j) {
            float a = 0.f;
#pragma unroll
            for (int k = 0; k < NTAPS; ++k) {
                a += tap[k] * s[16 + j - k];
            }
            acc[j] = a;
        }

        // Coalesced (64 lanes x 16 B contiguous) nontemporal store: full lines,
        // no partial-line write amplification, keeps y out of LLC so x stays hot.
        floatx4 out = {acc[0], acc[1], acc[2], acc[3]};
        __builtin_nontemporal_store(out, yv + idx);

        if (!have_next) break;
#pragma unroll
        for (int m = 0; m < 5; ++m) v[m] = w[m];
        idx = nidx;
    }
}

extern "C" void kernel_launch(void* const* d_in, const int* in_sizes, int n_in,
                              void* d_out, int out_size, void* d_ws, size_t ws_size,
                              hipStream_t stream)
{
    const float* x = (const float*)d_in[0];
    const float* b = (const float*)d_in[1];
    float* y = (float*)d_out;

    // Persistent-ish: 2048 blocks = 8 blocks/CU; ~15 chunk-iterations/thread.
    const int block = 256;
    const int grid = 2048;

    fir_apply_kernel<<<grid, block, 0, stream>>>(x, b, y);
}